// Round 4
// baseline (30.889 us; speedup 1.0000x reference)
//
#include <hip/hip_runtime.h>

constexpr int B   = 1024;
constexpr int T   = 8192;
constexpr int MS  = 128;
constexpr int CHK = 32;        // t-elements per chunk
constexpr int NCH = T / CHK;   // 256 chunks per row

// One block (256 threads = 4 waves) per batch row.
// Phase 1: fully-coalesced float4 loads (lane-contiguous); per-float4 channel
//          sums kept in registers, then LDS transpose so each thread owns the
//          16 contributors of one contiguous 32-t chunk.
// Phase 2: in-wave __shfl_up scan + cross-wave fixup -> chunk prefix E.
// Phase 3: 128 threads assemble segment sums from E + <=31-elem edge
//          corrections (L1/L2 hits), compute NLL in parallel.
// Phase 4: in-wave butterfly + one LDS hop -> partial[b] = (nll, count).
__global__ __launch_bounds__(256) void seg_loss_kernel(
    const float* __restrict__ logits,   // [B, T, 2]
    const int*   __restrict__ labels,   // [B, MS]
    const int*   __restrict__ bnd,      // [B, MS, 2]
    float*       __restrict__ partial)  // [B, 2]
{
    const int b    = blockIdx.x;
    const int tid  = threadIdx.x;
    const int lane = tid & 63;
    const int wave = tid >> 6;
    const float* row = logits + (size_t)b * T * 2;

    __shared__ float2 xsum[NCH][17];        // [chunk][contributor], pitch 17
    __shared__ float  e0[NCH + 1], e1[NCH + 1];
    __shared__ float  wtot0[4], wtot1[4];

    // ---- Phase 0: prefetch segment metadata ----
    int s_ = -1, e_ = -1, lab_ = 0;
    if (tid < MS) {
        const size_t bm = (size_t)b * MS + tid;
        s_   = bnd[bm * 2 + 0];
        e_   = bnd[bm * 2 + 1];
        lab_ = labels[bm];
    }

    // ---- Phase 1: coalesced loads; float4 index i = j*256 + tid ----
    // float4 i covers t = 2i, 2i+1: (x,y) = ch0/ch1 of t, (z,w) of t+1.
    {
        const float4* base = reinterpret_cast<const float4*>(row);
        float2 part[16];
        #pragma unroll
        for (int j = 0; j < 16; ++j) {
            float4 v = base[j * 256 + tid];
            part[j] = make_float2(v.x + v.z, v.y + v.w);
        }
        const int g = tid >> 4, h = tid & 15;
        #pragma unroll
        for (int j = 0; j < 16; ++j) {
            xsum[j * 16 + g][h] = part[j];   // row c = j*16+g holds float4s 16c..16c+15
        }
    }
    __syncthreads();

    // chunk sum for chunk c = tid (contributor h = float4 16c+h, in order)
    float s0 = 0.f, s1 = 0.f;
    #pragma unroll
    for (int h2 = 0; h2 < 16; ++h2) {
        float2 u = xsum[tid][h2];
        s0 += u.x; s1 += u.y;
    }

    // ---- Phase 2: inclusive scan (in-wave shuffle + cross-wave fixup) ----
    float x0 = s0, x1 = s1;
    #pragma unroll
    for (int off = 1; off < 64; off <<= 1) {
        float y0 = __shfl_up(x0, off, 64);
        float y1 = __shfl_up(x1, off, 64);
        if (lane >= off) { x0 += y0; x1 += y1; }
    }
    if (lane == 63) { wtot0[wave] = x0; wtot1[wave] = x1; }
    __syncthreads();
    float pre0 = 0.f, pre1 = 0.f;
    #pragma unroll
    for (int w = 0; w < 3; ++w) {
        if (wave > w) { pre0 += wtot0[w]; pre1 += wtot1[w]; }
    }
    e0[tid + 1] = x0 + pre0;
    e1[tid + 1] = x1 + pre1;
    if (tid == 0) { e0[0] = 0.f; e1[0] = 0.f; }
    __syncthreads();

    // ---- Phase 3: per-segment NLL (parallel over 128 segments) ----
    float nll = 0.f, cnt = 0.f;
    if (tid < MS && s_ != -1) {
        const int sc = min(max(s_, 0), T);
        const int ec = min(max(e_, 0), T);
        const int cs = sc >> 5;   // CHK = 32
        const int ce = ec >> 5;

        float q0 = e0[ce] - e0[cs];
        float q1 = e1[ce] - e1[cs];
        // head correction: subtract [cs*32, sc)
        for (int t = (cs << 5); t < sc; ++t) {
            float2 u = *reinterpret_cast<const float2*>(row + (size_t)t * 2);
            q0 -= u.x; q1 -= u.y;
        }
        // tail correction: add [ce*32, ec)
        for (int t = (ce << 5); t < ec; ++t) {
            float2 u = *reinterpret_cast<const float2*>(row + (size_t)t * 2);
            q0 += u.x; q1 += u.y;
        }

        const int len = ec - sc;
        float p0 = 0.f, p1 = 0.f;
        if (len > 0) {
            const float inv = 1.0f / (float)len;
            p0 = q0 * inv;
            p1 = q1 * inv;
        }
        const float mx  = fmaxf(p0, p1);
        const float lse = mx + logf(expf(p0 - mx) + expf(p1 - mx));
        nll = lse - ((lab_ == 0) ? p0 : p1);
        cnt = 1.0f;
    }

    // ---- Phase 4: in-wave butterfly + one LDS hop ----
    #pragma unroll
    for (int off = 32; off > 0; off >>= 1) {
        nll += __shfl_down(nll, off, 64);
        cnt += __shfl_down(cnt, off, 64);
    }
    __shared__ float rn[4], rc[4];
    if (lane == 0) { rn[wave] = nll; rc[wave] = cnt; }
    __syncthreads();
    if (tid == 0) {
        partial[(size_t)b * 2 + 0] = rn[0] + rn[1] + rn[2] + rn[3];
        partial[(size_t)b * 2 + 1] = rc[0] + rc[1] + rc[2] + rc[3];
    }
}

// Single-block finalize: BCE over B ranking logits + reduce per-row partials.
__global__ __launch_bounds__(256) void finalize_kernel(
    const float* __restrict__ rlogits,  // [B]
    const float* __restrict__ rlabels,  // [B]
    const float* __restrict__ partial,  // [B, 2]
    float*       __restrict__ out)      // [1]
{
    const int tid  = threadIdx.x;
    const int lane = tid & 63;
    const int wave = tid >> 6;

    float bce = 0.f;
    for (int i = tid; i < B; i += 256) {
        const float x = rlogits[i];
        const float y = rlabels[i];
        const float t     = log1pf(expf(-fabsf(x)));
        const float sp_px = fmaxf(x, 0.f) + t;   // softplus(x)
        const float sp_nx = fmaxf(-x, 0.f) + t;  // softplus(-x)
        bce += y * sp_nx + (1.f - y) * sp_px;
    }

    float nll = 0.f, cnt = 0.f;
    for (int i = tid; i < B; i += 256) {
        nll += partial[(size_t)i * 2 + 0];
        cnt += partial[(size_t)i * 2 + 1];
    }

    #pragma unroll
    for (int off = 32; off > 0; off >>= 1) {
        bce += __shfl_down(bce, off, 64);
        nll += __shfl_down(nll, off, 64);
        cnt += __shfl_down(cnt, off, 64);
    }
    __shared__ float sb[4], sn[4], sc[4];
    if (lane == 0) { sb[wave] = bce; sn[wave] = nll; sc[wave] = cnt; }
    __syncthreads();
    if (tid == 0) {
        const float tb = sb[0] + sb[1] + sb[2] + sb[3];
        const float tn = sn[0] + sn[1] + sn[2] + sn[3];
        const float tc = sc[0] + sc[1] + sc[2] + sc[3];
        const float rank  = tb / (float)B;
        const float prune = (tc > 0.f) ? (tn / tc) : 0.f;
        out[0] = 1.0f * rank + 0.5f * prune;
    }
}

extern "C" void kernel_launch(void* const* d_in, const int* in_sizes, int n_in,
                              void* d_out, int out_size, void* d_ws, size_t ws_size,
                              hipStream_t stream) {
    const float* rlogits = (const float*)d_in[0];  // ranking_logits [B]
    const float* rlabels = (const float*)d_in[1];  // ranking_labels [B]
    const float* plogits = (const float*)d_in[2];  // pruning_logits [B,T,C]
    const int*   plabels = (const int*)  d_in[3];  // pruning_labels [B,MS]
    const int*   bnd     = (const int*)  d_in[4];  // boundaries [B,MS,2]

    float* out     = (float*)d_out;
    float* partial = (float*)d_ws;  // B*2 floats, fully written by kernel 1

    seg_loss_kernel<<<B, 256, 0, stream>>>(plogits, plabels, bnd, partial);
    finalize_kernel<<<1, 256, 0, stream>>>(rlogits, rlabels, partial, out);
}

// Round 5
// 22.771 us; speedup vs baseline: 1.3565x; 1.3565x over previous
//
#include <hip/hip_runtime.h>

constexpr int B   = 1024;
constexpr int T   = 8192;
constexpr int MS  = 128;
constexpr int NF4 = T / 2;     // 4096 float4 positions per row (2 t's each)

// Padded LDS index for prefix entry k (k in [0, 4096]):
// idx(k) = k + (k>>4). For k = 16*tid + j (j<16) this is 17*tid + j.
__device__ __forceinline__ int pidx(int k) { return k + (k >> 4); }

// One block (256 threads = 4 waves) per batch row.
// Phase 1: thread tid loads its contiguous 32-t chunk (16 float4) and builds
//          the exclusive per-float4 prefix in registers.
// Phase 2: in-wave __shfl_up scan + cross-wave fixup -> thread-exclusive base;
//          write 2-t-granularity exclusive prefix E2[0..4096] to LDS.
// Phase 3: segment sum = E2[e>>1] - E2[s>>1] with <=2 scalar element fixups
//          (odd s/e). NLL fully parallel over 128 segments.
// Phase 4: in-wave butterfly + one LDS hop -> partial[b] = (nll, count).
__global__ __launch_bounds__(256) void seg_loss_kernel(
    const float* __restrict__ logits,   // [B, T, 2]
    const int*   __restrict__ labels,   // [B, MS]
    const int*   __restrict__ bnd,      // [B, MS, 2]
    float*       __restrict__ partial)  // [B, 2]
{
    const int b    = blockIdx.x;
    const int tid  = threadIdx.x;
    const int lane = tid & 63;
    const int wave = tid >> 6;
    const float* row = logits + (size_t)b * T * 2;

    __shared__ float2 E2[NF4 + (NF4 >> 4) + 2];   // padded 4097 entries ~34.9KB
    __shared__ float  wtot0[4], wtot1[4];
    __shared__ float  rn[4], rc[4];

    // ---- Phase 0: prefetch segment metadata ----
    int s_ = -1, e_ = -1, lab_ = 0;
    if (tid < MS) {
        const size_t bm = (size_t)b * MS + tid;
        s_   = bnd[bm * 2 + 0];
        e_   = bnd[bm * 2 + 1];
        lab_ = labels[bm];
    }

    // ---- Phase 1: load chunk, build exclusive per-float4 prefix ----
    float4 v[16];
    {
        const float4* p = reinterpret_cast<const float4*>(row) + (size_t)tid * 16;
        #pragma unroll
        for (int j = 0; j < 16; ++j) v[j] = p[j];
    }
    __builtin_amdgcn_sched_barrier(0);   // all 16 loads issued before compute
    float2 exv[16];
    float ex0 = 0.f, ex1 = 0.f;
    #pragma unroll
    for (int j = 0; j < 16; ++j) {
        exv[j] = make_float2(ex0, ex1);          // exclusive prefix at float4 j
        ex0 += v[j].x + v[j].z;
        ex1 += v[j].y + v[j].w;
    }
    // (ex0, ex1) = thread-chunk totals

    // ---- Phase 2: scan of thread totals -> thread-exclusive base ----
    float x0 = ex0, x1 = ex1;
    #pragma unroll
    for (int off = 1; off < 64; off <<= 1) {
        float y0 = __shfl_up(x0, off, 64);
        float y1 = __shfl_up(x1, off, 64);
        if (lane >= off) { x0 += y0; x1 += y1; }
    }
    if (lane == 63) { wtot0[wave] = x0; wtot1[wave] = x1; }
    __syncthreads();
    float pre0 = 0.f, pre1 = 0.f;
    #pragma unroll
    for (int w = 0; w < 3; ++w) {
        if (wave > w) { pre0 += wtot0[w]; pre1 += wtot1[w]; }
    }
    const float incl0 = x0 + pre0, incl1 = x1 + pre1;   // inclusive of this chunk
    const float excl0 = incl0 - ex0, excl1 = incl1 - ex1; // exclusive base

    // write 16 prefix entries (base 17*tid, contiguous)
    #pragma unroll
    for (int j = 0; j < 16; ++j) {
        E2[17 * tid + j] = make_float2(excl0 + exv[j].x, excl1 + exv[j].y);
    }
    if (tid == 255) E2[pidx(NF4)] = make_float2(incl0, incl1);  // k = 4096
    __syncthreads();

    // ---- Phase 3: per-segment NLL (parallel over 128 segments) ----
    float nll = 0.f, cnt = 0.f;
    if (tid < MS && s_ != -1) {
        const int sc = min(max(s_, 0), T);
        const int ec = min(max(e_, 0), T);
        const int cs = sc >> 1;
        const int ce = ec >> 1;

        const float2 Ps = E2[pidx(cs)];
        const float2 Pe = E2[pidx(ce)];
        float q0 = Pe.x - Ps.x;
        float q1 = Pe.y - Ps.y;
        if (sc & 1) {  // Pel(sc) = E2[cs] + elem(sc-1): subtract it
            float2 u = *reinterpret_cast<const float2*>(row + (size_t)(sc - 1) * 2);
            q0 -= u.x; q1 -= u.y;
        }
        if (ec & 1) {  // Pel(ec) = E2[ce] + elem(ec-1): add it
            float2 u = *reinterpret_cast<const float2*>(row + (size_t)(ec - 1) * 2);
            q0 += u.x; q1 += u.y;
        }

        const int len = ec - sc;
        float p0 = 0.f, p1 = 0.f;
        if (len > 0) {
            const float inv = 1.0f / (float)len;
            p0 = q0 * inv;
            p1 = q1 * inv;
        }
        const float mx  = fmaxf(p0, p1);
        const float lse = mx + logf(expf(p0 - mx) + expf(p1 - mx));
        nll = lse - ((lab_ == 0) ? p0 : p1);
        cnt = 1.0f;
    }

    // ---- Phase 4: in-wave butterfly + one LDS hop ----
    #pragma unroll
    for (int off = 32; off > 0; off >>= 1) {
        nll += __shfl_down(nll, off, 64);
        cnt += __shfl_down(cnt, off, 64);
    }
    if (lane == 0) { rn[wave] = nll; rc[wave] = cnt; }
    __syncthreads();
    if (tid == 0) {
        partial[(size_t)b * 2 + 0] = rn[0] + rn[1] + rn[2] + rn[3];
        partial[(size_t)b * 2 + 1] = rc[0] + rc[1] + rc[2] + rc[3];
    }
}

// Single-block finalize: BCE over B ranking logits + reduce per-row partials.
__global__ __launch_bounds__(256) void finalize_kernel(
    const float* __restrict__ rlogits,  // [B]
    const float* __restrict__ rlabels,  // [B]
    const float* __restrict__ partial,  // [B, 2]
    float*       __restrict__ out)      // [1]
{
    const int tid  = threadIdx.x;
    const int lane = tid & 63;
    const int wave = tid >> 6;

    float bce = 0.f;
    for (int i = tid; i < B; i += 256) {
        const float x = rlogits[i];
        const float y = rlabels[i];
        const float t     = log1pf(expf(-fabsf(x)));
        const float sp_px = fmaxf(x, 0.f) + t;   // softplus(x)
        const float sp_nx = fmaxf(-x, 0.f) + t;  // softplus(-x)
        bce += y * sp_nx + (1.f - y) * sp_px;
    }

    float nll = 0.f, cnt = 0.f;
    for (int i = tid; i < B; i += 256) {
        nll += partial[(size_t)i * 2 + 0];
        cnt += partial[(size_t)i * 2 + 1];
    }

    #pragma unroll
    for (int off = 32; off > 0; off >>= 1) {
        bce += __shfl_down(bce, off, 64);
        nll += __shfl_down(nll, off, 64);
        cnt += __shfl_down(cnt, off, 64);
    }
    __shared__ float sb[4], sn[4], sc[4];
    if (lane == 0) { sb[wave] = bce; sn[wave] = nll; sc[wave] = cnt; }
    __syncthreads();
    if (tid == 0) {
        const float tb = sb[0] + sb[1] + sb[2] + sb[3];
        const float tn = sn[0] + sn[1] + sn[2] + sn[3];
        const float tc = sc[0] + sc[1] + sc[2] + sc[3];
        const float rank  = tb / (float)B;
        const float prune = (tc > 0.f) ? (tn / tc) : 0.f;
        out[0] = 1.0f * rank + 0.5f * prune;
    }
}

extern "C" void kernel_launch(void* const* d_in, const int* in_sizes, int n_in,
                              void* d_out, int out_size, void* d_ws, size_t ws_size,
                              hipStream_t stream) {
    const float* rlogits = (const float*)d_in[0];  // ranking_logits [B]
    const float* rlabels = (const float*)d_in[1];  // ranking_labels [B]
    const float* plogits = (const float*)d_in[2];  // pruning_logits [B,T,C]
    const int*   plabels = (const int*)  d_in[3];  // pruning_labels [B,MS]
    const int*   bnd     = (const int*)  d_in[4];  // boundaries [B,MS,2]

    float* out     = (float*)d_out;
    float* partial = (float*)d_ws;  // B*2 floats, fully written by kernel 1

    seg_loss_kernel<<<B, 256, 0, stream>>>(plogits, plabels, bnd, partial);
    finalize_kernel<<<1, 256, 0, stream>>>(rlogits, rlabels, partial, out);
}